// Round 8
// baseline (325.660 us; speedup 1.0000x reference)
//
#include <hip/hip_runtime.h>

// EncoderBlock: pre-LN MHSA + pre-LN GELU FFN.  S=2048 D=1024 H=16 DK=64 MLP=4096.
// 10-dispatch pipeline: prep (all weight transposes + bias concat, one launch),
// ln1, QKV-gemm, vtrans, flash, O-proj gemm (splitK2), fused reduce+ln2, FFN1,
// FFN2 (splitK4), final reduce.
// GEMMs: 128x256 tile, 8 waves, BK=64, triple-buffered LDS (144KB), prefetch
// depth 2, counted s_waitcnt vmcnt(6) (T4) -- now with TWO barrier-delimited
// phases per K-tile (T3 fine interleave: {stage || ds_read} -> barrier ->
// lgkmcnt(0) -> setprio -> 16 MFMA -> setprio -> barrier), m196/m218b lever.
// Attention: round-0 proven flash kernel (66.5 us, reproduced 4x).

constexpr int kS = 2048, kD = 1024, kH = 16, kDK = 64, kMLP = 4096;
constexpr float kEps = 1e-5f;

using u16 = unsigned short;
using u32 = unsigned int;
typedef float f32x4 __attribute__((ext_vector_type(4)));
typedef short bf16x8 __attribute__((ext_vector_type(8)));   // 8 bf16 = 4 VGPRs

__device__ __forceinline__ u16 f2b(float f) {               // fp32 -> bf16 (RNE)
  u32 u = __builtin_bit_cast(u32, f);
  return (u16)((u + 0x7fffu + ((u >> 16) & 1u)) >> 16);
}

typedef const __attribute__((address_space(1))) u32* gas1;
typedef __attribute__((address_space(3))) u32* las3;
__device__ __forceinline__ void async16(const void* g, void* l) {
  // global -> LDS DMA, 16B/lane; LDS dest = wave-uniform base + lane*16
  __builtin_amdgcn_global_load_lds((gas1)g, (las3)l, 16, 0, 0);
}

// ---------------- LayerNorm: fp32 [row][1024] -> bf16 ----------------
__global__ __launch_bounds__(256)
void ln_kernel(const float* __restrict__ x, const float* __restrict__ g,
               const float* __restrict__ b, u16* __restrict__ out) {
  __shared__ float red[8];
  const int row = blockIdx.x, tid = threadIdx.x;
  const float4 v = *(const float4*)(x + (size_t)row * kD + tid * 4);
  float s = v.x + v.y + v.z + v.w;
  float ss = v.x * v.x + v.y * v.y + v.z * v.z + v.w * v.w;
#pragma unroll
  for (int d = 1; d < 64; d <<= 1) { s += __shfl_xor(s, d); ss += __shfl_xor(ss, d); }
  if ((tid & 63) == 0) { red[tid >> 6] = s; red[4 + (tid >> 6)] = ss; }
  __syncthreads();
  const float m = (red[0] + red[1] + red[2] + red[3]) * (1.f / kD);
  const float var = (red[4] + red[5] + red[6] + red[7]) * (1.f / kD) - m * m;
  const float r = rsqrtf(var + kEps);
  const float4 gv = *(const float4*)(g + tid * 4);
  const float4 bv = *(const float4*)(b + tid * 4);
  ushort4 o;
  o.x = f2b((v.x - m) * r * gv.x + bv.x);
  o.y = f2b((v.y - m) * r * gv.y + bv.y);
  o.z = f2b((v.z - m) * r * gv.z + bv.z);
  o.w = f2b((v.w - m) * r * gv.w + bv.w);
  *(ushort4*)(out + (size_t)row * kD + tid * 4) = o;
}

// ------- prep: ALL weight transposes (fp32 -> bf16, out[c][r]=in[r][c]) + bias
// concat, in ONE launch.  Block-range dispatch:
//   [0,4096): wq/wk/wv/wo (1024 tiles each)   [4096,8192): w1   [8192,12288): w2
//   [12288,12300): bqkv concat (12 x 256 elems)
__global__ __launch_bounds__(256)
void prep(const float* __restrict__ wq, const float* __restrict__ wk,
          const float* __restrict__ wv, const float* __restrict__ wo,
          const float* __restrict__ w1, const float* __restrict__ w2,
          const float* __restrict__ bq, const float* __restrict__ bk,
          const float* __restrict__ bv, u16* __restrict__ wqkvt,
          u16* __restrict__ wot, u16* __restrict__ w1t, u16* __restrict__ w2t,
          float* __restrict__ bqkv) {
  const int bid = blockIdx.x;
  const int x = threadIdx.x, y = threadIdx.y;
  if (bid >= 12288) {  // concat (block-uniform branch; no barrier executed here)
    int i = (bid - 12288) * 256 + y * 32 + x;
    bqkv[i] = i < kD ? bq[i] : (i < 2 * kD ? bk[i - kD] : bv[i - 2 * kD]);
    return;
  }
  const float* in; u16* out; int R, C, t;
  if (bid < 4096) {
    int j = bid >> 10; t = bid & 1023; R = kD; C = kD;
    in = j == 0 ? wq : j == 1 ? wk : j == 2 ? wv : wo;
    out = j == 3 ? wot : wqkvt + (size_t)j * kD * kD;
  } else if (bid < 8192) {
    t = bid - 4096; R = kD; C = kMLP; in = w1; out = w1t;
  } else {
    t = bid - 8192; R = kMLP; C = kD; in = w2; out = w2t;
  }
  const int nbx = C >> 5;
  const int c0 = (t % nbx) * 32, r0 = (t / nbx) * 32;
  __shared__ float tile[32][33];
#pragma unroll
  for (int i = 0; i < 4; ++i)
    tile[y + i * 8][x] = in[(size_t)(r0 + y + i * 8) * C + c0 + x];
  __syncthreads();
#pragma unroll
  for (int i = 0; i < 4; ++i)
    out[(size_t)(c0 + y + i * 8) * R + r0 + x] = f2b(tile[x][y + i * 8]);
}

// --- per-head V transpose: qkv[s][2048+h*64+d] (bf16) -> vt[h][d][s] (bf16) ---
__global__ __launch_bounds__(256)
void vtrans(const u16* __restrict__ qkv, u16* __restrict__ vt) {
  __shared__ u16 t[64][72];
  const int s0 = blockIdx.x * 64, h = blockIdx.y, tid = threadIdx.x;
#pragma unroll
  for (int r = 0; r < 2; ++r) {
    int chunk = r * 256 + tid, row = chunk >> 3, col = (chunk & 7) * 8;
    uint4 v = *(const uint4*)(qkv + (size_t)(s0 + row) * 3072 + 2 * kD + h * 64 + col);
    *(uint4*)(&t[row][col]) = v;
  }
  __syncthreads();
#pragma unroll
  for (int r = 0; r < 2; ++r) {
    int chunk = r * 256 + tid, drow = chunk >> 3, scol = (chunk & 7) * 8;
    u16 tmp[8];
#pragma unroll
    for (int j = 0; j < 8; ++j) tmp[j] = t[scol + j][drow];
    *(uint4*)(vt + (size_t)h * 64 * kS + (size_t)drow * kS + s0 + scol) = *(uint4*)tmp;
  }
}

// ---------------- bt-GEMM: C[M,N] = A[M,K](bf16) x Bt[N,K](bf16) ----------------
// 128x256 tile, BK=64, 8 waves (2M x 4N, each 64x64 out), 32 MFMA/K-tile/wave.
// Triple buffer, prefetch depth 2.  TWO phases per K-tile (kk=0,1), each:
//   {3 staging async16 || 8 ds_read_b128} -> s_barrier -> lgkmcnt(0) ->
//   sched_barrier -> setprio(1) -> 16 MFMA -> setprio(0) -> s_barrier
// Counted s_waitcnt vmcnt(6) once per K-tile (before the tile's final barrier);
// vmcnt(0) only when no prefetch remains.  Addressing identical to the
// verified kernel: LDS [row][chunk ^ (row&7)], pre-inverse-swizzled source.
template <int EPI>
__global__ __launch_bounds__(512, 1)
void gemm_bt(const u16* __restrict__ A, const u16* __restrict__ Bt,
             const float* __restrict__ bias, void* __restrict__ Cout,
             int N, int K, int Ksub) {
  constexpr int BM = 128, BN = 256, BK = 64;
  __shared__ u16 As[3][BM * BK];   // 3 x 16 KB
  __shared__ u16 Bs[3][BN * BK];   // 3 x 32 KB   (total 144 KB)
  const int tid = threadIdx.x;
  const int w = tid >> 6, l = tid & 63;
  const int wm = w >> 2, wn = w & 3;           // 2 x 4 wave grid
  const int ln = l & 15, q = l >> 4;
  const int row0 = blockIdx.y * BM, col0 = blockIdx.x * BN;
  const int koff = blockIdx.z * Ksub;
  const int nIter = Ksub / BK;

  const int rS = tid >> 3;
  const int cS = ((tid & 7) ^ (rS & 7)) * 8;
  const u16* Ab0 = A + (size_t)(row0 + rS) * K + koff + cS;
  const u16* Bb0 = Bt + (size_t)(col0 + rS) * K + koff + cS;
  const int dW = w * 512;

  f32x4 acc[4][4] = {};

  auto stage = [&](int t, int b) {             // prologue only: all 6
    const int kt = t * BK;
    async16(Ab0 + kt, &As[b][dW]);
    async16(Ab0 + (size_t)64 * K + kt, &As[b][4096 + dW]);
    async16(Bb0 + kt, &Bs[b][dW]);
    async16(Bb0 + (size_t)64 * K + kt, &Bs[b][4096 + dW]);
    async16(Bb0 + (size_t)128 * K + kt, &Bs[b][8192 + dW]);
    async16(Bb0 + (size_t)192 * K + kt, &Bs[b][12288 + dW]);
  };

  stage(0, 0);
  stage(1, 1);
  asm volatile("s_waitcnt vmcnt(6)" ::: "memory");   // tile 0 landed; tile 1 in flight
  __builtin_amdgcn_s_barrier();
  __builtin_amdgcn_sched_barrier(0);

  int bR = 0, bW = 2;
  for (int t = 0; t < nIter; ++t) {
    const u16* Ar = As[bR];
    const u16* Br = Bs[bR];
    const bool pf = (t + 2 < nIter);
    const int kt2 = (t + 2) * BK;
    // ================= phase 0 (kk = 0) =================
    if (pf) {                                   // first 3 of tile t+2's 6 DMAs
      async16(Ab0 + kt2, &As[bW][dW]);
      async16(Ab0 + (size_t)64 * K + kt2, &As[bW][4096 + dW]);
      async16(Bb0 + kt2, &Bs[bW][dW]);
    }
    {
      bf16x8 af[4], bf[4];
      const int ch = (q ^ (ln & 7)) * 8;        // ks=0 chunk
#pragma unroll
      for (int i = 0; i < 4; ++i)
        af[i] = *(const bf16x8*)(Ar + (wm * 64 + i * 16 + ln) * 64 + ch);
#pragma unroll
      for (int j = 0; j < 4; ++j)
        bf[j] = *(const bf16x8*)(Br + (wn * 64 + j * 16 + ln) * 64 + ch);
      __builtin_amdgcn_s_barrier();
      asm volatile("s_waitcnt lgkmcnt(0)" ::: "memory");
      __builtin_amdgcn_sched_barrier(0);
      __builtin_amdgcn_s_setprio(1);
#pragma unroll
      for (int i = 0; i < 4; ++i)
#pragma unroll
        for (int j = 0; j < 4; ++j)
          acc[i][j] = __builtin_amdgcn_mfma_f32_16x16x32_bf16(af[i], bf[j], acc[i][j], 0, 0, 0);
      __builtin_amdgcn_s_setprio(0);
      __builtin_amdgcn_s_barrier();
    }
    // ================= phase 1 (kk = 1) =================
    if (pf) {                                   // remaining 3 DMAs of tile t+2
      async16(Bb0 + (size_t)64 * K + kt2, &Bs[bW][4096 + dW]);
      async16(Bb0 + (size_t)128 * K + kt2, &Bs[bW][8192 + dW]);
      async16(Bb0 + (size_t)192 * K + kt2, &Bs[bW][12288 + dW]);
    }
    {
      bf16x8 af[4], bf[4];
      const int ch = ((4 + q) ^ (ln & 7)) * 8;  // ks=1 chunk
#pragma unroll
      for (int i = 0; i < 4; ++i)
        af[i] = *(const bf16x8*)(Ar + (wm * 64 + i * 16 + ln) * 64 + ch);
#pragma unroll
      for (int j = 0; j < 4; ++j)
        bf[j] = *(const bf16x8*)(Br + (wn * 64 + j * 16 + ln) * 64 + ch);
      __builtin_amdgcn_s_barrier();
      asm volatile("s_waitcnt lgkmcnt(0)" ::: "memory");
      __builtin_amdgcn_sched_barrier(0);
      __builtin_amdgcn_s_setprio(1);
#pragma unroll
      for (int i = 0; i < 4; ++i)
#pragma unroll
        for (int j = 0; j < 4; ++j)
          acc[i][j] = __builtin_amdgcn_mfma_f32_16x16x32_bf16(af[i], bf[j], acc[i][j], 0, 0, 0);
      __builtin_amdgcn_s_setprio(0);
    }
    // counted drain: t+1's 6 DMAs done, t+2's 6 stay in flight (never 0 mid-loop)
    if (pf) asm volatile("s_waitcnt vmcnt(6)" ::: "memory");
    else    asm volatile("s_waitcnt vmcnt(0)" ::: "memory");
    __builtin_amdgcn_s_barrier();
    __builtin_amdgcn_sched_barrier(0);
    bR = bR == 2 ? 0 : bR + 1;
    bW = bW == 2 ? 0 : bW + 1;
  }

  float* Pf = nullptr;
  if constexpr (EPI == 3)
    Pf = (float*)Cout + (size_t)blockIdx.z * gridDim.y * BM * N;
#pragma unroll
  for (int i = 0; i < 4; ++i) {
    const int row = row0 + wm * 64 + i * 16 + q * 4;
#pragma unroll
    for (int j = 0; j < 4; ++j) {
      const int col = col0 + wn * 64 + j * 16 + ln;
      float bb = 0.f;
      if constexpr (EPI != 3) bb = bias[col];
#pragma unroll
      for (int r = 0; r < 4; ++r) {
        const size_t idx = (size_t)(row + r) * N + col;
        float v = acc[i][j][r] + bb;
        if constexpr (EPI == 0) {
          ((u16*)Cout)[idx] = f2b(v);
        } else if constexpr (EPI == 1) {
          ((u16*)Cout)[idx] = f2b(0.5f * v * (1.f + erff(v * 0.7071067811865475f)));
        } else {
          Pf[idx] = v;
        }
      }
    }
  }
}

// ---- split-K reduce: out = sum_s parts[s] + bias + res  (fp32, float4) ----
template <int KS>
__global__ __launch_bounds__(256)
void reduce_add(const float* __restrict__ parts, const float* __restrict__ bias,
                const float* __restrict__ res, float* __restrict__ out,
                int N, size_t strideMN) {
  const size_t b = ((size_t)blockIdx.x * 256 + threadIdx.x) * 4;
  float4 a = *(const float4*)(res + b);
  const float4 bv = *(const float4*)(bias + (b & (size_t)(N - 1)));
  a.x += bv.x; a.y += bv.y; a.z += bv.z; a.w += bv.w;
#pragma unroll
  for (int s = 0; s < KS; ++s) {
    const float4 p = *(const float4*)(parts + s * strideMN + b);
    a.x += p.x; a.y += p.y; a.z += p.z; a.w += p.w;
  }
  *(float4*)(out + b) = a;
}

// ---- fused split-K reduce + LayerNorm: x2 = res+bias+sum(parts) (fp32 out),
// h2 = LN(x2)*g+b (bf16 out).  One row per block, 256 thr. ----
template <int KS>
__global__ __launch_bounds__(256)
void reduce_ln(const float* __restrict__ parts, const float* __restrict__ bias,
               const float* __restrict__ res, const float* __restrict__ g,
               const float* __restrict__ b, float* __restrict__ x2out,
               u16* __restrict__ h2out, size_t strideMN) {
  __shared__ float red[8];
  const int row = blockIdx.x, tid = threadIdx.x;
  const size_t base = (size_t)row * kD + tid * 4;
  float4 a = *(const float4*)(res + base);
  const float4 bv = *(const float4*)(bias + tid * 4);
  a.x += bv.x; a.y += bv.y; a.z += bv.z; a.w += bv.w;
#pragma unroll
  for (int s = 0; s < KS; ++s) {
    const float4 p = *(const float4*)(parts + s * strideMN + base);
    a.x += p.x; a.y += p.y; a.z += p.z; a.w += p.w;
  }
  *(float4*)(x2out + base) = a;
  float s1 = a.x + a.y + a.z + a.w;
  float ss = a.x * a.x + a.y * a.y + a.z * a.z + a.w * a.w;
#pragma unroll
  for (int d = 1; d < 64; d <<= 1) { s1 += __shfl_xor(s1, d); ss += __shfl_xor(ss, d); }
  if ((tid & 63) == 0) { red[tid >> 6] = s1; red[4 + (tid >> 6)] = ss; }
  __syncthreads();
  const float m = (red[0] + red[1] + red[2] + red[3]) * (1.f / kD);
  const float var = (red[4] + red[5] + red[6] + red[7]) * (1.f / kD) - m * m;
  const float rr = rsqrtf(var + kEps);
  const float4 gv = *(const float4*)(g + tid * 4);
  const float4 bbv = *(const float4*)(b + tid * 4);
  ushort4 o;
  o.x = f2b((a.x - m) * rr * gv.x + bbv.x);
  o.y = f2b((a.y - m) * rr * gv.y + bbv.y);
  o.z = f2b((a.z - m) * rr * gv.z + bbv.z);
  o.w = f2b((a.w - m) * rr * gv.w + bbv.w);
  *(ushort4*)(h2out + base) = o;
}

// ---------------- flash attention (round-0 proven version) ----------------
// grid (S/64, H), 256 thr (4 waves); wave w owns q-rows [q0+w*16, +16).
__global__ __launch_bounds__(256, 2)
void flash_attn(const u16* __restrict__ qkv, const u16* __restrict__ vt,
                u16* __restrict__ og) {
  constexpr int LQ = 72;    // 64 + 8 pad (breaks b128 bank conflicts)
  constexpr int LV = 136;   // 128 + 8 pad
  __shared__ u16 Qs[64 * LQ];
  __shared__ u16 Ks[128 * LQ];
  __shared__ u16 Vs[64 * LV];       // V^T tile: [d][s]
  __shared__ u16 Ps[4][16 * LV];    // per-wave P (C-layout -> A-layout round trip)
  const int tid = threadIdx.x, w = tid >> 6, l = tid & 63;
  const int h = blockIdx.y, q0 = blockIdx.x * 64;

  // stage Q [64][64]
#pragma unroll
  for (int r = 0; r < 2; ++r) {
    int chunk = r * 256 + tid, row = chunk >> 3, col = (chunk & 7) * 8;
    uint4 v = *(const uint4*)(qkv + (size_t)(q0 + row) * 3072 + h * 64 + col);
    *(uint4*)(&Qs[row * LQ + col]) = v;
  }
  __syncthreads();
  bf16x8 qa[2];
#pragma unroll
  for (int kq = 0; kq < 2; ++kq)
    qa[kq] = *(const bf16x8*)(&Qs[(w * 16 + (l & 15)) * LQ + kq * 32 + (l >> 4) * 8]);

  f32x4 oacc[4] = {};
  float mi[4], li[4];
#pragma unroll
  for (int r = 0; r < 4; ++r) { mi[r] = -1e30f; li[r] = 0.f; }

  for (int kt = 0; kt < kS; kt += 128) {
    __syncthreads();  // prev iter done reading Ks/Vs
    // stage K-tile [128][64]
#pragma unroll
    for (int r = 0; r < 4; ++r) {
      int chunk = r * 256 + tid, row = chunk >> 3, col = (chunk & 7) * 8;
      uint4 v = *(const uint4*)(qkv + (size_t)(kt + row) * 3072 + kD + h * 64 + col);
      *(uint4*)(&Ks[row * LQ + col]) = v;
    }
    // stage V^T tile [64][128]
#pragma unroll
    for (int r = 0; r < 4; ++r) {
      int chunk = r * 256 + tid, row = chunk >> 4, col = (chunk & 15) * 8;
      uint4 v = *(const uint4*)(vt + (size_t)h * 64 * kS + (size_t)row * kS + kt + col);
      *(uint4*)(&Vs[row * LV + col]) = v;
    }
    __syncthreads();

    // S = Q K^T  (16 q-rows x 128 cols per wave)
    f32x4 s[8];
#pragma unroll
    for (int n = 0; n < 8; ++n) {
      f32x4 z = {};
      bf16x8 kb0 = *(const bf16x8*)(&Ks[(n * 16 + (l & 15)) * LQ + (l >> 4) * 8]);
      bf16x8 kb1 = *(const bf16x8*)(&Ks[(n * 16 + (l & 15)) * LQ + 32 + (l >> 4) * 8]);
      z = __builtin_amdgcn_mfma_f32_16x16x32_bf16(qa[0], kb0, z, 0, 0, 0);
      z = __builtin_amdgcn_mfma_f32_16x16x32_bf16(qa[1], kb1, z, 0, 0, 0);
      s[n] = z;
    }
    // online softmax (rows live on 16 lanes sharing l>>4; cols = l&15 across 8 frags)
    float alpha[4];
#pragma unroll
    for (int r = 0; r < 4; ++r) {
      float m = -1e30f;
#pragma unroll
      for (int n = 0; n < 8; ++n) m = fmaxf(m, s[n][r]);
#pragma unroll
      for (int d = 1; d < 16; d <<= 1) m = fmaxf(m, __shfl_xor(m, d));
      m *= 0.125f;  // 1/sqrt(DK); positive scale commutes with max
      float mn = fmaxf(mi[r], m);
      alpha[r] = __expf(mi[r] - mn);
      mi[r] = mn;
      li[r] *= alpha[r];
    }
#pragma unroll
    for (int n = 0; n < 4; ++n)
#pragma unroll
      for (int r = 0; r < 4; ++r) oacc[n][r] *= alpha[r];
    float rs[4] = {0.f, 0.f, 0.f, 0.f};
#pragma unroll
    for (int n = 0; n < 8; ++n)
#pragma unroll
      for (int r = 0; r < 4; ++r) {
        float pv = __expf(s[n][r] * 0.125f - mi[r]);
        rs[r] += pv;
        Ps[w][((l >> 4) * 4 + r) * LV + n * 16 + (l & 15)] = f2b(pv);
      }
#pragma unroll
    for (int r = 0; r < 4; ++r) {
      float t = rs[r];
#pragma unroll
      for (int d = 1; d < 16; d <<= 1) t += __shfl_xor(t, d);
      li[r] += t;
    }
    // O += P V   (P 16x128 from own-wave LDS region; V^T in Vs)
    bf16x8 pa[4];
#pragma unroll
    for (int ks = 0; ks < 4; ++ks)
      pa[ks] = *(const bf16x8*)(&Ps[w][(l & 15) * LV + ks * 32 + (l >> 4) * 8]);
#pragma unroll
    for (int n = 0; n < 4; ++n)
#pragma unroll
      for (int ks = 0; ks < 4; ++ks) {
        bf16x8 vb = *(const bf16x8*)(&Vs[(n * 16 + (l & 15)) * LV + ks * 32 + (l >> 4) * 8]);
        oacc[n] = __builtin_amdgcn_mfma_f32_16x16x32_bf16(pa[ks], vb, oacc[n], 0, 0, 0);
      }
  }
  // epilogue: normalize, write og[h][s][d] (contiguous == reference reshape)
#pragma unroll
  for (int r = 0; r < 4; ++r) {
    float inv = 1.f / li[r];
    int srow = q0 + w * 16 + (l >> 4) * 4 + r;
#pragma unroll
    for (int n = 0; n < 4; ++n) {
      int d = n * 16 + (l & 15);
      og[(size_t)h * kS * kDK + (size_t)srow * kDK + d] = f2b(oacc[n][r] * inv);
    }
  }
}

extern "C" void kernel_launch(void* const* d_in, const int* in_sizes, int n_in,
                              void* d_out, int out_size, void* d_ws, size_t ws_size,
                              hipStream_t stream) {
  const float* x = (const float*)d_in[0];
  const float* wq = (const float*)d_in[1];
  const float* bq = (const float*)d_in[2];
  const float* wk = (const float*)d_in[3];
  const float* bk = (const float*)d_in[4];
  const float* wv = (const float*)d_in[5];
  const float* bv = (const float*)d_in[6];
  const float* wo = (const float*)d_in[7];
  const float* bo = (const float*)d_in[8];
  const float* w1 = (const float*)d_in[9];
  const float* b1 = (const float*)d_in[10];
  const float* w2 = (const float*)d_in[11];
  const float* b2 = (const float*)d_in[12];
  const float* ln1g = (const float*)d_in[13];
  const float* ln1b = (const float*)d_in[14];
  const float* ln2g = (const float*)d_in[15];
  const float* ln2b = (const float*)d_in[16];
  float* out = (float*)d_out;

  // Workspace plan. "pool" buffers are all dead by the time the split-K
  // partials are written, so partials alias pool base.  O-proj partials (z=2,
  // 16.8 MB) stay inside [h1..qkv) -- og (at ~26 MB) remains live and safe.
  char* p = (char*)d_ws;
  auto alloc = [&](size_t bytes) { void* q = (void*)p; p += (bytes + 255) & ~(size_t)255; return q; };
  u16* h1 = (u16*)alloc((size_t)kS * kD * 2);
  u16* wqkvt = (u16*)alloc((size_t)3 * kD * kD * 2);
  u16* qkv = (u16*)alloc((size_t)kS * 3 * kD * 2);
  u16* vt = (u16*)alloc((size_t)kH * kDK * kS * 2);
  u16* og = (u16*)alloc((size_t)kS * kD * 2);
  u16* wot = (u16*)alloc((size_t)kD * kD * 2);
  u16* h2 = (u16*)alloc((size_t)kS * kD * 2);
  u16* w1t = (u16*)alloc((size_t)kD * kMLP * 2);
  float* bqkv = (float*)alloc((size_t)3 * kD * 4);
  float* x2 = (float*)alloc((size_t)kS * kD * 4);
  u16* fbuf = (u16*)alloc((size_t)kS * kMLP * 2);
  u16* w2t = (u16*)alloc((size_t)kMLP * kD * 2);
  float* part = (float*)d_ws;  // aliases pool (see plan above)
  const size_t strideMN = (size_t)kS * kD;

  // one launch: all 6 weight transposes + bias concat
  prep<<<dim3(12300), dim3(32, 8), 0, stream>>>(
      wq, wk, wv, wo, w1, w2, bq, bk, bv, wqkvt, wot, w1t, w2t, bqkv);

  ln_kernel<<<dim3(kS), dim3(256), 0, stream>>>(x, ln1g, ln1b, h1);
  // fused QKV: [2048,1024] x [3072,1024]^T -> qkv bf16 [2048,3072]
  gemm_bt<0><<<dim3(3 * kD / 256, kS / 128, 1), dim3(512), 0, stream>>>(
      h1, wqkvt, bqkv, qkv, 3 * kD, kD, kD);
  vtrans<<<dim3(kS / 64, kH), dim3(256), 0, stream>>>(qkv, vt);
  flash_attn<<<dim3(kS / 64, kH), dim3(256), 0, stream>>>(qkv, vt, og);
  // O-proj split-K=2: partials = og @ wo  (fp32)
  gemm_bt<3><<<dim3(kD / 256, kS / 128, 2), dim3(512), 0, stream>>>(
      og, wot, nullptr, part, kD, kD, kD / 2);
  // fused: x2 = x + part0 + part1 + bo ; h2 = LN(x2)
  reduce_ln<2><<<dim3(kS), dim3(256), 0, stream>>>(
      part, bo, x, ln2g, ln2b, x2, h2, strideMN);
  // FFN1 + exact GELU -> bf16 [2048,4096]
  gemm_bt<1><<<dim3(kMLP / 256, kS / 128, 1), dim3(512), 0, stream>>>(
      h2, w1t, b1, fbuf, kMLP, kD, kD);
  // FFN2 split-K=4: partials = gelu @ w2  (fp32)
  gemm_bt<3><<<dim3(kD / 256, kS / 128, 4), dim3(512), 0, stream>>>(
      fbuf, w2t, nullptr, part, kD, kMLP, kMLP / 4);
  // out = x2 + sum(parts) + b2
  reduce_add<4><<<dim3(kS * kD / 4 / 256), dim3(256), 0, stream>>>(
      part, b2, x2, out, kD, strideMN);
}

// Round 10
// 299.925 us; speedup vs baseline: 1.0858x; 1.0858x over previous
//
#include <hip/hip_runtime.h>

// EncoderBlock: pre-LN MHSA + pre-LN GELU FFN.  S=2048 D=1024 H=16 DK=64 MLP=4096.
// 10-dispatch pipeline: prep, ln1, QKV-gemm, vtrans, flash, O-proj (splitK2),
// fused reduce+ln2, FFN1, FFN2 (splitK4), final reduce.
// GEMMs: round-5 proven deep-pipe (128x256, 8 waves, BK=64, triple-buffer,
// prefetch depth 2, ONE counted vmcnt(6) + ONE barrier pair per K-tile).
// Attention: round-0 compute/softmax/P path, K/V staging rebuilt as
// double-buffered global_load_lds + counted vmcnt(8): tile t+1's DMAs issue at
// top of iter t, waited top of iter t+1 -> staging latency hidden under a full
// tile of compute.  Unpadded LDS + XOR chunk swizzle (chunk16 ^= row&7).
// Q via direct global loads, force-consumed BEFORE staging so the compiler's
// Q-waitcnt lands pre-loop (prevents a conservative vmcnt(0) inside the loop).

constexpr int kS = 2048, kD = 1024, kH = 16, kDK = 64, kMLP = 4096;
constexpr float kEps = 1e-5f;

using u16 = unsigned short;
using u32 = unsigned int;
typedef float f32x4 __attribute__((ext_vector_type(4)));
typedef short bf16x8 __attribute__((ext_vector_type(8)));   // 8 bf16 = 4 VGPRs

__device__ __forceinline__ u16 f2b(float f) {               // fp32 -> bf16 (RNE)
  u32 u = __builtin_bit_cast(u32, f);
  return (u16)((u + 0x7fffu + ((u >> 16) & 1u)) >> 16);
}

typedef const __attribute__((address_space(1))) u32* gas1;
typedef __attribute__((address_space(3))) u32* las3;
__device__ __forceinline__ void async16(const void* g, void* l) {
  // global -> LDS DMA, 16B/lane; LDS dest = wave-uniform base + lane*16
  __builtin_amdgcn_global_load_lds((gas1)g, (las3)l, 16, 0, 0);
}

// ---------------- LayerNorm: fp32 [row][1024] -> bf16 ----------------
__global__ __launch_bounds__(256)
void ln_kernel(const float* __restrict__ x, const float* __restrict__ g,
               const float* __restrict__ b, u16* __restrict__ out) {
  __shared__ float red[8];
  const int row = blockIdx.x, tid = threadIdx.x;
  const float4 v = *(const float4*)(x + (size_t)row * kD + tid * 4);
  float s = v.x + v.y + v.z + v.w;
  float ss = v.x * v.x + v.y * v.y + v.z * v.z + v.w * v.w;
#pragma unroll
  for (int d = 1; d < 64; d <<= 1) { s += __shfl_xor(s, d); ss += __shfl_xor(ss, d); }
  if ((tid & 63) == 0) { red[tid >> 6] = s; red[4 + (tid >> 6)] = ss; }
  __syncthreads();
  const float m = (red[0] + red[1] + red[2] + red[3]) * (1.f / kD);
  const float var = (red[4] + red[5] + red[6] + red[7]) * (1.f / kD) - m * m;
  const float r = rsqrtf(var + kEps);
  const float4 gv = *(const float4*)(g + tid * 4);
  const float4 bv = *(const float4*)(b + tid * 4);
  ushort4 o;
  o.x = f2b((v.x - m) * r * gv.x + bv.x);
  o.y = f2b((v.y - m) * r * gv.y + bv.y);
  o.z = f2b((v.z - m) * r * gv.z + bv.z);
  o.w = f2b((v.w - m) * r * gv.w + bv.w);
  *(ushort4*)(out + (size_t)row * kD + tid * 4) = o;
}

// ------- prep: ALL weight transposes (fp32 -> bf16, out[c][r]=in[r][c]) + bias
// concat, in ONE launch. ----
__global__ __launch_bounds__(256)
void prep(const float* __restrict__ wq, const float* __restrict__ wk,
          const float* __restrict__ wv, const float* __restrict__ wo,
          const float* __restrict__ w1, const float* __restrict__ w2,
          const float* __restrict__ bq, const float* __restrict__ bk,
          const float* __restrict__ bv, u16* __restrict__ wqkvt,
          u16* __restrict__ wot, u16* __restrict__ w1t, u16* __restrict__ w2t,
          float* __restrict__ bqkv) {
  const int bid = blockIdx.x;
  const int x = threadIdx.x, y = threadIdx.y;
  if (bid >= 12288) {  // concat (block-uniform branch; no barrier executed here)
    int i = (bid - 12288) * 256 + y * 32 + x;
    bqkv[i] = i < kD ? bq[i] : (i < 2 * kD ? bk[i - kD] : bv[i - 2 * kD]);
    return;
  }
  const float* in; u16* out; int R, C, t;
  if (bid < 4096) {
    int j = bid >> 10; t = bid & 1023; R = kD; C = kD;
    in = j == 0 ? wq : j == 1 ? wk : j == 2 ? wv : wo;
    out = j == 3 ? wot : wqkvt + (size_t)j * kD * kD;
  } else if (bid < 8192) {
    t = bid - 4096; R = kD; C = kMLP; in = w1; out = w1t;
  } else {
    t = bid - 8192; R = kMLP; C = kD; in = w2; out = w2t;
  }
  const int nbx = C >> 5;
  const int c0 = (t % nbx) * 32, r0 = (t / nbx) * 32;
  __shared__ float tile[32][33];
#pragma unroll
  for (int i = 0; i < 4; ++i)
    tile[y + i * 8][x] = in[(size_t)(r0 + y + i * 8) * C + c0 + x];
  __syncthreads();
#pragma unroll
  for (int i = 0; i < 4; ++i)
    out[(size_t)(c0 + y + i * 8) * R + r0 + x] = f2b(tile[x][y + i * 8]);
}

// --- per-head V transpose: qkv[s][2048+h*64+d] (bf16) -> vt[h][d][s] (bf16) ---
__global__ __launch_bounds__(256)
void vtrans(const u16* __restrict__ qkv, u16* __restrict__ vt) {
  __shared__ u16 t[64][72];
  const int s0 = blockIdx.x * 64, h = blockIdx.y, tid = threadIdx.x;
#pragma unroll
  for (int r = 0; r < 2; ++r) {
    int chunk = r * 256 + tid, row = chunk >> 3, col = (chunk & 7) * 8;
    uint4 v = *(const uint4*)(qkv + (size_t)(s0 + row) * 3072 + 2 * kD + h * 64 + col);
    *(uint4*)(&t[row][col]) = v;
  }
  __syncthreads();
#pragma unroll
  for (int r = 0; r < 2; ++r) {
    int chunk = r * 256 + tid, drow = chunk >> 3, scol = (chunk & 7) * 8;
    u16 tmp[8];
#pragma unroll
    for (int j = 0; j < 8; ++j) tmp[j] = t[scol + j][drow];
    *(uint4*)(vt + (size_t)h * 64 * kS + (size_t)drow * kS + s0 + scol) = *(uint4*)tmp;
  }
}

// ---------------- bt-GEMM: C[M,N] = A[M,K](bf16) x Bt[N,K](bf16) ----------------
// 128x256 tile, BK=64, 8 waves (2M x 4N, each 64x64 out), 32 MFMA/K-step/wave.
// Triple buffer, prefetch depth 2, one counted s_waitcnt vmcnt(6) + one s_barrier
// pair per K-step.  LDS [row][chunk ^ (row&7)], pre-inverse-swizzled source.
// (round-5 version; measured best of 5 GEMM structures, 305.4 us total)
template <int EPI>
__global__ __launch_bounds__(512, 1)
void gemm_bt(const u16* __restrict__ A, const u16* __restrict__ Bt,
             const float* __restrict__ bias, void* __restrict__ Cout,
             int N, int K, int Ksub) {
  constexpr int BM = 128, BN = 256, BK = 64;
  __shared__ u16 As[3][BM * BK];   // 3 x 16 KB
  __shared__ u16 Bs[3][BN * BK];   // 3 x 32 KB   (total 144 KB)
  const int tid = threadIdx.x;
  const int w = tid >> 6, l = tid & 63;
  const int wm = w >> 2, wn = w & 3;           // 2 x 4 wave grid
  const int ln = l & 15, q = l >> 4;
  const int row0 = blockIdx.y * BM, col0 = blockIdx.x * BN;
  const int koff = blockIdx.z * Ksub;
  const int nIter = Ksub / BK;

  const int rS = tid >> 3;
  const int cS = ((tid & 7) ^ (rS & 7)) * 8;
  const u16* Ab0 = A + (size_t)(row0 + rS) * K + koff + cS;
  const u16* Bb0 = Bt + (size_t)(col0 + rS) * K + koff + cS;
  const int dW = w * 512;

  f32x4 acc[4][4] = {};

  auto stage = [&](int t, int b) {             // 6 async16 per wave
    const int kt = t * BK;
    async16(Ab0 + kt, &As[b][dW]);
    async16(Ab0 + (size_t)64 * K + kt, &As[b][4096 + dW]);
    async16(Bb0 + kt, &Bs[b][dW]);
    async16(Bb0 + (size_t)64 * K + kt, &Bs[b][4096 + dW]);
    async16(Bb0 + (size_t)128 * K + kt, &Bs[b][8192 + dW]);
    async16(Bb0 + (size_t)192 * K + kt, &Bs[b][12288 + dW]);
  };

  stage(0, 0);
  stage(1, 1);
  asm volatile("s_waitcnt vmcnt(6)" ::: "memory");   // tile 0 landed; tile 1 in flight
  __builtin_amdgcn_s_barrier();
  __builtin_amdgcn_sched_barrier(0);

  int bR = 0, bW = 2;
  for (int t = 0; t < nIter; ++t) {
    if (t + 2 < nIter) stage(t + 2, bW);
    const u16* Ar = As[bR];
    const u16* Br = Bs[bR];
#pragma unroll
    for (int ks = 0; ks < 2; ++ks) {
      const int ch = ((ks * 4 + q) ^ (ln & 7)) * 8;
      bf16x8 af[4], bf[4];
#pragma unroll
      for (int i = 0; i < 4; ++i)
        af[i] = *(const bf16x8*)(Ar + (wm * 64 + i * 16 + ln) * 64 + ch);
#pragma unroll
      for (int j = 0; j < 4; ++j)
        bf[j] = *(const bf16x8*)(Br + (wn * 64 + j * 16 + ln) * 64 + ch);
      __builtin_amdgcn_s_setprio(1);
#pragma unroll
      for (int i = 0; i < 4; ++i)
#pragma unroll
        for (int j = 0; j < 4; ++j)
          acc[i][j] = __builtin_amdgcn_mfma_f32_16x16x32_bf16(af[i], bf[j], acc[i][j], 0, 0, 0);
      __builtin_amdgcn_s_setprio(0);
    }
    if (t + 2 < nIter) asm volatile("s_waitcnt vmcnt(6)" ::: "memory");
    else               asm volatile("s_waitcnt vmcnt(0)" ::: "memory");
    __builtin_amdgcn_s_barrier();
    __builtin_amdgcn_sched_barrier(0);
    bR = bR == 2 ? 0 : bR + 1;
    bW = bW == 2 ? 0 : bW + 1;
  }

  float* Pf = nullptr;
  if constexpr (EPI == 3)
    Pf = (float*)Cout + (size_t)blockIdx.z * gridDim.y * BM * N;
#pragma unroll
  for (int i = 0; i < 4; ++i) {
    const int row = row0 + wm * 64 + i * 16 + q * 4;
#pragma unroll
    for (int j = 0; j < 4; ++j) {
      const int col = col0 + wn * 64 + j * 16 + ln;
      float bb = 0.f;
      if constexpr (EPI != 3) bb = bias[col];
#pragma unroll
      for (int r = 0; r < 4; ++r) {
        const size_t idx = (size_t)(row + r) * N + col;
        float v = acc[i][j][r] + bb;
        if constexpr (EPI == 0) {
          ((u16*)Cout)[idx] = f2b(v);
        } else if constexpr (EPI == 1) {
          ((u16*)Cout)[idx] = f2b(0.5f * v * (1.f + erff(v * 0.7071067811865475f)));
        } else {
          Pf[idx] = v;
        }
      }
    }
  }
}

// ---- split-K reduce: out = sum_s parts[s] + bias + res  (fp32, float4) ----
template <int KS>
__global__ __launch_bounds__(256)
void reduce_add(const float* __restrict__ parts, const float* __restrict__ bias,
                const float* __restrict__ res, float* __restrict__ out,
                int N, size_t strideMN) {
  const size_t b = ((size_t)blockIdx.x * 256 + threadIdx.x) * 4;
  float4 a = *(const float4*)(res + b);
  const float4 bv = *(const float4*)(bias + (b & (size_t)(N - 1)));
  a.x += bv.x; a.y += bv.y; a.z += bv.z; a.w += bv.w;
#pragma unroll
  for (int s = 0; s < KS; ++s) {
    const float4 p = *(const float4*)(parts + s * strideMN + b);
    a.x += p.x; a.y += p.y; a.z += p.z; a.w += p.w;
  }
  *(float4*)(out + b) = a;
}

// ---- fused split-K reduce + LayerNorm ----
template <int KS>
__global__ __launch_bounds__(256)
void reduce_ln(const float* __restrict__ parts, const float* __restrict__ bias,
               const float* __restrict__ res, const float* __restrict__ g,
               const float* __restrict__ b, float* __restrict__ x2out,
               u16* __restrict__ h2out, size_t strideMN) {
  __shared__ float red[8];
  const int row = blockIdx.x, tid = threadIdx.x;
  const size_t base = (size_t)row * kD + tid * 4;
  float4 a = *(const float4*)(res + base);
  const float4 bv = *(const float4*)(bias + tid * 4);
  a.x += bv.x; a.y += bv.y; a.z += bv.z; a.w += bv.w;
#pragma unroll
  for (int s = 0; s < KS; ++s) {
    const float4 p = *(const float4*)(parts + s * strideMN + base);
    a.x += p.x; a.y += p.y; a.z += p.z; a.w += p.w;
  }
  *(float4*)(x2out + base) = a;
  float s1 = a.x + a.y + a.z + a.w;
  float ss = a.x * a.x + a.y * a.y + a.z * a.z + a.w * a.w;
#pragma unroll
  for (int d = 1; d < 64; d <<= 1) { s1 += __shfl_xor(s1, d); ss += __shfl_xor(ss, d); }
  if ((tid & 63) == 0) { red[tid >> 6] = s1; red[4 + (tid >> 6)] = ss; }
  __syncthreads();
  const float m = (red[0] + red[1] + red[2] + red[3]) * (1.f / kD);
  const float var = (red[4] + red[5] + red[6] + red[7]) * (1.f / kD) - m * m;
  const float rr = rsqrtf(var + kEps);
  const float4 gv = *(const float4*)(g + tid * 4);
  const float4 bbv = *(const float4*)(b + tid * 4);
  ushort4 o;
  o.x = f2b((a.x - m) * rr * gv.x + bbv.x);
  o.y = f2b((a.y - m) * rr * gv.y + bbv.y);
  o.z = f2b((a.z - m) * rr * gv.z + bbv.z);
  o.w = f2b((a.w - m) * rr * gv.w + bbv.w);
  *(ushort4*)(h2out + base) = o;
}

// ---------------- flash attention (dbuf global_load_lds staging) ----------------
// grid (S/64, H), 256 thr (4 waves); wave w owns q-rows [q0+w*16, +16).
// Compute/softmax/P semantics identical to the round-0 proven kernel; only the
// LDS layouts (unpadded + chunk16^=(row&7) XOR swizzle) and staging/sync moved.
// Per tile: {stage t+1 via 8 async16/wave -> vmcnt(8) counted} -> s_barrier ->
// QK^T/softmax/P/PV -> s_barrier (protects buf[cur] before restage at t+1).
__global__ __launch_bounds__(256, 2)
void flash_attn(const u16* __restrict__ qkv, const u16* __restrict__ vt,
                u16* __restrict__ og) {
  __shared__ u16 Ks[2][128 * 64];   // [row][chunk16 ^ (row&7)]  2 x 16 KB
  __shared__ u16 Vs[2][64 * 128];   // V^T [d][s-chunk swz]      2 x 16 KB
  __shared__ u16 Ps[4][16 * 128];   // per-wave P, swizzled      16 KB   (total 80 KB)
  const int tid = threadIdx.x, w = tid >> 6, l = tid & 63;
  const int t4 = l >> 4, ln = l & 15;
  const int h = blockIdx.y, q0 = blockIdx.x * 64;
  constexpr int NT = kS / 128;

  // Q fragments: 2 direct 16B global loads, force-consumed BEFORE staging so
  // the compiler's waitcnt for them lands HERE (only these 2 loads pending),
  // never inside the pipelined loop.
  bf16x8 qa[2];
#pragma unroll
  for (int kq = 0; kq < 2; ++kq)
    qa[kq] = *(const bf16x8*)(qkv + (size_t)(q0 + w * 16 + ln) * 3072 + h * 64 + kq * 32 + t4 * 8);
  {
    u32 u0 = ((const u32*)&qa[0])[0], u1 = ((const u32*)&qa[1])[0];
    asm volatile("" :: "v"(u0), "v"(u1));
  }

  // staging: call c = w*4+i covers 1024B of LDS; lane l -> dest base + l*16B.
  // K call c: rows c*8 + (l>>3), chunk = l&7, src chunk' = (l&7)^(l>>3).
  const u16* ksrc = qkv + kD + h * 64 + (size_t)(l >> 3) * 3072 + (((l & 7) ^ (l >> 3)) * 8);
  auto stageK = [&](int kt, int buf) {
#pragma unroll
    for (int i = 0; i < 4; ++i) {
      const int c = w * 4 + i;
      async16(ksrc + (size_t)(kt + c * 8) * 3072, &Ks[buf][c * 512]);
    }
  };
  // V call c: rows c*4 + (l>>4), chunk16 = l&15, src chunk' = (l&15)^((c&1)*4 + (l>>4)).
  auto stageV = [&](int kt, int buf) {
#pragma unroll
    for (int i = 0; i < 4; ++i) {
      const int c = w * 4 + i;
      const int row = c * 4 + (l >> 4);
      const int ch = (l & 15) ^ (((c & 1) * 4) + (l >> 4));
      async16(vt + (size_t)h * kDK * kS + (size_t)row * kS + kt + ch * 8, &Vs[buf][c * 512]);
    }
  };

  stageK(0, 0);
  stageV(0, 0);

  f32x4 oacc[4] = {};
  float mi[4], li[4];
#pragma unroll
  for (int r = 0; r < 4; ++r) { mi[r] = -1e30f; li[r] = 0.f; }

  for (int t = 0; t < NT; ++t) {
    const int cur = t & 1;
    const int kt = t * 128;
    if (t + 1 < NT) {
      stageK(kt + 128, cur ^ 1);
      stageV(kt + 128, cur ^ 1);
      asm volatile("s_waitcnt vmcnt(8)" ::: "memory");  // tile t's 8 DMAs landed
    } else {
      asm volatile("s_waitcnt vmcnt(0)" ::: "memory");
    }
    __builtin_amdgcn_s_barrier();            // all waves' tile-t DMAs visible
    __builtin_amdgcn_sched_barrier(0);       // keep ds_reads below the wait

    // S = Q K^T  (16 q-rows x 128 cols per wave); kb row n*16+ln, chunks t4 / 4+t4
    const u16* Kb = Ks[cur];
    f32x4 s[8];
#pragma unroll
    for (int n = 0; n < 8; ++n) {
      f32x4 z = {};
      const int row = n * 16 + ln;
      bf16x8 kb0 = *(const bf16x8*)(Kb + row * 64 + ((t4 ^ (ln & 7)) * 8));
      bf16x8 kb1 = *(const bf16x8*)(Kb + row * 64 + (((4 + t4) ^ (ln & 7)) * 8));
      z = __builtin_amdgcn_mfma_f32_16x16x32_bf16(qa[0], kb0, z, 0, 0, 0);
      z = __builtin_amdgcn_mfma_f32_16x16x32_bf16(qa[1], kb1, z, 0, 0, 0);
      s[n] = z;
    }
    // online softmax (identical to proven kernel)
    float alpha[4];
#pragma unroll
    for (int r = 0; r < 4; ++r) {
      float m = -1e30f;
#pragma unroll
      for (int n = 0; n < 8; ++n) m = fmaxf(m, s[n][r]);
#pragma unroll
      for (int d = 1; d < 16; d <<= 1) m = fmaxf(m, __shfl_xor(m, d));
      m *= 0.125f;  // 1/sqrt(DK); positive scale commutes with max
      float mn = fmaxf(mi[r], m);
      alpha[r] = __expf(mi[r] - mn);
      mi[r] = mn;
      li[r] *= alpha[r];
    }
#pragma unroll
    for (int n = 0; n < 4; ++n)
#pragma unroll
      for (int r = 0; r < 4; ++r) oacc[n][r] *= alpha[r];
    float rs[4] = {0.f, 0.f, 0.f, 0.f};
#pragma unroll
    for (int n = 0; n < 8; ++n)
#pragma unroll
      for (int r = 0; r < 4; ++r) {
        float pv = __expf(s[n][r] * 0.125f - mi[r]);
        rs[r] += pv;
        // P[qrow][col=n*16+ln]: chunk16 = 2n+(ln>>3) ^ (qrow&7), off = ln&7
        const int qrow = t4 * 4 + r;
        Ps[w][qrow * 128 + (((2 * n + (ln >> 3)) ^ (qrow & 7)) * 8) + (ln & 7)] = f2b(pv);
      }
#pragma unroll
    for (int r = 0; r < 4; ++r) {
      float t2 = rs[r];
#pragma unroll
      for (int d = 1; d < 16; d <<= 1) t2 += __shfl_xor(t2, d);
      li[r] += t2;
    }
    // O += P V   (pa row = ln, chunk16 = ks*4+t4; vb row = n*16+ln, same chunk)
    const u16* Vb = Vs[cur];
    bf16x8 pa[4];
#pragma unroll
    for (int ks = 0; ks < 4; ++ks)
      pa[ks] = *(const bf16x8*)(&Ps[w][ln * 128 + (((ks * 4 + t4) ^ (ln & 7)) * 8)]);
#pragma unroll
    for (int n = 0; n < 4; ++n)
#pragma unroll
      for (int ks = 0; ks < 4; ++ks) {
        const int row = n * 16 + ln;
        bf16x8 vb = *(const bf16x8*)(Vb + row * 128 + (((ks * 4 + t4) ^ (ln & 7)) * 8));
        oacc[n] = __builtin_amdgcn_mfma_f32_16x16x32_bf16(pa[ks], vb, oacc[n], 0, 0, 0);
      }
    __builtin_amdgcn_s_barrier();   // all waves done reading buf[cur] before restage
  }
  // epilogue: normalize, write og[h][s][d] (contiguous == reference reshape)
#pragma unroll
  for (int r = 0; r < 4; ++r) {
    float inv = 1.f / li[r];
    int srow = q0 + w * 16 + t4 * 4 + r;
#pragma unroll
    for (int n = 0; n < 4; ++n) {
      int d = n * 16 + ln;
      og[(size_t)h * kS * kDK + (size_t)srow * kDK + d] = f2b(oacc[n][r] * inv);
    }
  }
}

extern "C" void kernel_launch(void* const* d_in, const int* in_sizes, int n_in,
                              void* d_out, int out_size, void* d_ws, size_t ws_size,
                              hipStream_t stream) {
  const float* x = (const float*)d_in[0];
  const float* wq = (const float*)d_in[1];
  const float* bq = (const float*)d_in[2];
  const float* wk = (const float*)d_in[3];
  const float* bk = (const float*)d_in[4];
  const float* wv = (const float*)d_in[5];
  const float* bv = (const float*)d_in[6];
  const float* wo = (const float*)d_in[7];
  const float* bo = (const float*)d_in[8];
  const float* w1 = (const float*)d_in[9];
  const float* b1 = (const float*)d_in[10];
  const float* w2 = (const float*)d_in[11];
  const float* b2 = (const float*)d_in[12];
  const float* ln1g = (const float*)d_in[13];
  const float* ln1b = (const float*)d_in[14];
  const float* ln2g = (const float*)d_in[15];
  const float* ln2b = (const float*)d_in[16];
  float* out = (float*)d_out;

  // Workspace plan. "pool" buffers are all dead by the time the split-K
  // partials are written, so partials alias pool base.
  char* p = (char*)d_ws;
  auto alloc = [&](size_t bytes) { void* q = (void*)p; p += (bytes + 255) & ~(size_t)255; return q; };
  u16* h1 = (u16*)alloc((size_t)kS * kD * 2);
  u16* wqkvt = (u16*)alloc((size_t)3 * kD * kD * 2);
  u16* qkv = (u16*)alloc((size_t)kS * 3 * kD * 2);
  u16* vt = (u16*)alloc((size_t)kH * kDK * kS * 2);
  u16* og = (u16*)alloc((size_t)kS * kD * 2);
  u16* wot = (u16*)alloc((size_t)kD * kD * 2);
  u16* h2 = (u16*)alloc((size_t)kS * kD * 2);
  u16* w1t = (u16*)alloc((size_t)kD * kMLP * 2);
  float* bqkv = (float*)alloc((size_t)3 * kD * 4);
  float* x2 = (float*)alloc((size_t)kS * kD * 4);
  u16* fbuf = (u16*)alloc((size_t)kS * kMLP * 2);
  u16* w2t = (u16*)alloc((size_t)kMLP * kD * 2);
  float* part = (float*)d_ws;  // aliases pool (see plan above)
  const size_t strideMN = (size_t)kS * kD;

  // one launch: all 6 weight transposes + bias concat
  prep<<<dim3(12300), dim3(32, 8), 0, stream>>>(
      wq, wk, wv, wo, w1, w2, bq, bk, bv, wqkvt, wot, w1t, w2t, bqkv);

  ln_kernel<<<dim3(kS), dim3(256), 0, stream>>>(x, ln1g, ln1b, h1);
  // fused QKV: [2048,1024] x [3072,1024]^T -> qkv bf16 [2048,3072]
  gemm_bt<0><<<dim3(3 * kD / 256, kS / 128, 1), dim3(512), 0, stream>>>(
      h1, wqkvt, bqkv, qkv, 3 * kD, kD, kD);
  vtrans<<<dim3(kS / 64, kH), dim3(256), 0, stream>>>(qkv, vt);
  flash_attn<<<dim3(kS / 64, kH), dim3(256), 0, stream>>>(qkv, vt, og);
  // O-proj split-K=2: partials = og @ wo  (fp32)
  gemm_bt<3><<<dim3(kD / 256, kS / 128, 2), dim3(512), 0, stream>>>(
      og, wot, nullptr, part, kD, kD, kD / 2);
  // fused: x2 = x + part0 + part1 + bo ; h2 = LN(x2)
  reduce_ln<2><<<dim3(kS), dim3(256), 0, stream>>>(
      part, bo, x, ln2g, ln2b, x2, h2, strideMN);
  // FFN1 + exact GELU -> bf16 [2048,4096]
  gemm_bt<1><<<dim3(kMLP / 256, kS / 128, 1), dim3(512), 0, stream>>>(
      h2, w1t, b1, fbuf, kMLP, kD, kD);
  // FFN2 split-K=4: partials = gelu @ w2  (fp32)
  gemm_bt<3><<<dim3(kD / 256, kS / 128, 4), dim3(512), 0, stream>>>(
      fbuf, w2t, nullptr, part, kD, kMLP, kMLP / 4);
  // out = x2 + sum(parts) + b2
  reduce_add<4><<<dim3(kS * kD / 4 / 256), dim3(256), 0, stream>>>(
      part, b2, x2, out, kD, strideMN);
}